// Round 6
// baseline (147.724 us; speedup 1.0000x reference)
//
#include <hip/hip_runtime.h>
#include <stdint.h>

#define BB 64
#define LL 512
#define DD 300
#define CC 128
#define NP 64  // partials per batch (16 token-chunks x 4 token-groups)

// ws layout (floats):
//   Gpart : [64][64][3][300] = 3,686,400  (per-(chunk,token-group) partials)
//   Gred  : [64][900]        =    57,600  (float4 view: [64][225])
//   W2    : [128][900]       =   115,200  (fused sim.fc weights)
//   bias2 : [128]
#define OFF_GRED  (BB * NP * 3 * DD)
#define OFF_W2    (OFF_GRED + BB * 3 * DD)
#define OFF_BIAS2 (OFF_W2 + CC * 3 * DD)

// ---------------------------------------------------------------------------
// DECOMPOSITION PROBE ROUND: k_gather is launched TWICE (idempotent — both
// launches compute and write identical values). dur_us minus the 131 µs
// baseline = duration of a WARM (L3-resident embed) gather pass. See theory.
// ---------------------------------------------------------------------------
__global__ __launch_bounds__(320) void k_gather(
    const int* __restrict__ x, const float* __restrict__ embed,
    const float* __restrict__ conv_w, const float* __restrict__ conv_b,
    const float* __restrict__ w3, const float* __restrict__ b3,
    const float* __restrict__ w4, const float* __restrict__ b4,
    const float* __restrict__ w5, const float* __restrict__ b5,
    const float* __restrict__ fcw, const float* __restrict__ fcb,
    float* __restrict__ Gpart, float* __restrict__ W2,
    float* __restrict__ bias2) {
  const int blk = blockIdx.x;
  const int tid = threadIdx.x;

  if (blk < 1024) {  // ---------------- gather ----------------
    const int b = blk >> 4;
    const int tc = blk & 15;

    __shared__ int sx[32];
    __shared__ float su[3][32];

    if (tid < 32) {
      const int t = tc * 32 + tid;
      sx[tid] = x[b * LL + t];
      const float* ws[3] = {w3, w4, w5};
#pragma unroll
      for (int kk = 0; kk < 3; ++kk) {
        const int k = kk + 3;
        int lo = t - k + 1; if (lo < 0) lo = 0;
        int hi = t; const int lim = LL - k - 1; if (hi > lim) hi = lim;
        float s = 0.f;
        for (int l = lo; l <= hi; ++l) s += ws[kk][l];
        su[kk][tid] = s;
      }
    }
    __syncthreads();

    if (tid < 300) {
      const int tg = tid / 75;        // token-group 0..3 (8 tokens each)
      const int d4 = tid - tg * 75;   // float4 slot 0..74
      const int i0 = tg * 8;

      float4 v[8];
#pragma unroll
      for (int i = 0; i < 8; ++i) {
        const float4* rp = (const float4*)(embed + (size_t)sx[i0 + i] * DD);
        v[i] = rp[d4];
      }

      float4 a0 = {0.f, 0.f, 0.f, 0.f};
      float4 a1 = {0.f, 0.f, 0.f, 0.f};
      float4 a2 = {0.f, 0.f, 0.f, 0.f};
#pragma unroll
      for (int i = 0; i < 8; ++i) {
        const int j = i0 + i;
        const float w0 = su[0][j], w1 = su[1][j], w2 = su[2][j];
        a0.x += w0 * v[i].x; a0.y += w0 * v[i].y;
        a0.z += w0 * v[i].z; a0.w += w0 * v[i].w;
        a1.x += w1 * v[i].x; a1.y += w1 * v[i].y;
        a1.z += w1 * v[i].z; a1.w += w1 * v[i].w;
        a2.x += w2 * v[i].x; a2.y += w2 * v[i].y;
        a2.z += w2 * v[i].z; a2.w += w2 * v[i].w;
      }

      const int p = tc * 4 + tg;  // 0..63
      float* Gp = Gpart + (size_t)(b * NP + p) * (3 * DD);
      ((float4*)(Gp + 0 * DD))[d4] = a0;
      ((float4*)(Gp + 1 * DD))[d4] = a1;
      ((float4*)(Gp + 2 * DD))[d4] = a2;
    }
  } else if (blk < 1408) {  // ---------------- W2 precompute ----------------
    const int w = (blk - 1024) * 5 + (tid >> 6);  // 0..1919
    const int lane = tid & 63;
    const int c = w / 15;
    const int rem = w - c * 15;
    const int kk = rem / 5;
    const int chunk = rem - kk * 5;
    const int d = chunk * 64 + lane;
    if (d < DD) {
      const float* fr = fcw + c * (3 * CC) + kk * CC;  // 128 wave-uniform
      float acc0 = 0.f, acc1 = 0.f;
#pragma unroll 4
      for (int cp = 0; cp < CC; cp += 2) {
        acc0 += fr[cp] * conv_w[cp * DD + d];
        acc1 += fr[cp + 1] * conv_w[(cp + 1) * DD + d];
      }
      W2[c * (3 * DD) + kk * DD + d] = acc0 + acc1;
    }
  } else {  // ---------------- bias2 ----------------
    const int wid = tid >> 6;
    const int lane = tid & 63;
    const int c = (blk - 1408) * 5 + wid;  // 0..129, guard below
    if (c < CC) {
      float sk[3];
      const float* ws[3] = {w3, w4, w5};
#pragma unroll
      for (int kk = 0; kk < 3; ++kk) {
        const int len = LL - (kk + 3);
        float s = 0.f;
        for (int l = lane; l < len; l += 64) s += ws[kk][l];
#pragma unroll
        for (int off = 32; off >= 1; off >>= 1) s += __shfl_down(s, off, 64);
        sk[kk] = __shfl(s, 0, 64);
      }
      const float bkv[3] = {b3[0], b4[0], b5[0]};
      float acc = 0.f;
#pragma unroll
      for (int s6 = 0; s6 < 6; ++s6) {
        const int j = s6 * 64 + lane;
        const int kk = j >> 7;
        const int cp = j & 127;
        acc += fcw[c * (3 * CC) + j] * (conv_b[cp] * sk[kk] + bkv[kk]);
      }
#pragma unroll
      for (int off = 32; off >= 1; off >>= 1) acc += __shfl_down(acc, off, 64);
      if (lane == 0) bias2[c] = acc + fcb[c];
    }
  }
}

// ---------------------------------------------------------------------------
// Kernel 2: Gpart -> Gred reduction. 900 blocks x 256 threads; 16 threads
// per float4 output (14,400 outputs), each sums 4 of the 64 partials,
// then 4-step shuffle.
// ---------------------------------------------------------------------------
__global__ __launch_bounds__(256) void k_reduce(
    const float* __restrict__ Gpart, float* __restrict__ Gred) {
  const int gid = blockIdx.x * 256 + threadIdx.x;  // < 230400
  const int o = gid >> 4;   // float4 output id, < 14400
  const int r = gid & 15;   // partial-quad group 0..15
  const int b = o / 225;
  const int q = o - b * 225;
  const float4* gp =
      (const float4*)Gpart + ((size_t)b * NP + r * 4) * 225 + q;
  const float4 v0 = gp[0];
  const float4 v1 = gp[225];
  const float4 v2 = gp[450];
  const float4 v3 = gp[675];
  float4 s;
  s.x = (v0.x + v1.x) + (v2.x + v3.x);
  s.y = (v0.y + v1.y) + (v2.y + v3.y);
  s.z = (v0.z + v1.z) + (v2.z + v3.z);
  s.w = (v0.w + v1.w) + (v2.w + v3.w);
#pragma unroll
  for (int off = 1; off <= 8; off <<= 1) {
    s.x += __shfl_down(s.x, off, 64);
    s.y += __shfl_down(s.y, off, 64);
    s.z += __shfl_down(s.z, off, 64);
    s.w += __shfl_down(s.w, off, 64);
  }
  if (r == 0) ((float4*)Gred)[o] = s;
}

// ---------------------------------------------------------------------------
// Kernel 3: head GEMV, 1024 blocks x 256 threads. Wave wg -> channel pair
// (c0,c0+1) of batch b: out[b,c] = <W2[c,:], Gred[b,:]> + bias2[c].
// ---------------------------------------------------------------------------
__global__ __launch_bounds__(256) void k_out(
    const float* __restrict__ Gred, const float* __restrict__ W2,
    const float* __restrict__ bias2, float* __restrict__ out) {
  const int wg = blockIdx.x * 4 + (threadIdx.x >> 6);  // 0..4095
  const int lane = threadIdx.x & 63;
  const int b = wg >> 6;        // 0..63
  const int c0 = (wg & 63) * 2; // channel pair

  const float2* gr = (const float2*)(Gred + b * (3 * DD));    // 450 float2
  const float2* wr0 = (const float2*)(W2 + c0 * (3 * DD));
  const float2* wr1 = (const float2*)(W2 + (c0 + 1) * (3 * DD));
  float a0 = 0.f, a1 = 0.f;
#pragma unroll
  for (int s = 0; s < 7; ++s) {
    const float2 g = gr[s * 64 + lane];
    const float2 va = wr0[s * 64 + lane];
    const float2 vb = wr1[s * 64 + lane];
    a0 += va.x * g.x + va.y * g.y;
    a1 += vb.x * g.x + vb.y * g.y;
  }
  if (lane < 2) {
    const float2 g = gr[448 + lane];
    const float2 va = wr0[448 + lane];
    const float2 vb = wr1[448 + lane];
    a0 += va.x * g.x + va.y * g.y;
    a1 += vb.x * g.x + vb.y * g.y;
  }
#pragma unroll
  for (int off = 32; off >= 1; off >>= 1) {
    a0 += __shfl_down(a0, off, 64);
    a1 += __shfl_down(a1, off, 64);
  }
  if (lane == 0) {
    out[b * CC + c0] = a0 + bias2[c0];
    out[b * CC + c0 + 1] = a1 + bias2[c0 + 1];
  }
}

// ---------------------------------------------------------------------------
extern "C" void kernel_launch(void* const* d_in, const int* in_sizes, int n_in,
                              void* d_out, int out_size, void* d_ws,
                              size_t ws_size, hipStream_t stream) {
  const int* x = (const int*)d_in[0];
  const float* embed = (const float*)d_in[1];
  const float* conv_w = (const float*)d_in[2];
  const float* conv_b = (const float*)d_in[3];
  const float* fc3w = (const float*)d_in[4];
  const float* fc3b = (const float*)d_in[5];
  const float* fc4w = (const float*)d_in[6];
  const float* fc4b = (const float*)d_in[7];
  const float* fc5w = (const float*)d_in[8];
  const float* fc5b = (const float*)d_in[9];
  const float* fcw = (const float*)d_in[10];
  const float* fcb = (const float*)d_in[11];

  float* Gpart = (float*)d_ws;
  float* Gred = (float*)d_ws + OFF_GRED;
  float* W2 = (float*)d_ws + OFF_W2;
  float* bias2 = (float*)d_ws + OFF_BIAS2;

  // PROBE: two identical (idempotent) gather dispatches. Pass 1 = cold L3,
  // pass 2 = warm L3. dur_us - 131 isolates the warm-gather duration.
  k_gather<<<dim3(1434), dim3(320), 0, stream>>>(
      x, embed, conv_w, conv_b, fc3w, fc3b, fc4w, fc4b, fc5w, fc5b, fcw, fcb,
      Gpart, W2, bias2);
  k_gather<<<dim3(1434), dim3(320), 0, stream>>>(
      x, embed, conv_w, conv_b, fc3w, fc3b, fc4w, fc4b, fc5w, fc5b, fcw, fcb,
      Gpart, W2, bias2);
  k_reduce<<<dim3(900), dim3(256), 0, stream>>>(Gpart, Gred);
  k_out<<<dim3(1024), dim3(256), 0, stream>>>(Gred, W2, bias2,
                                              (float*)d_out);
}

// Round 7
// 133.287 us; speedup vs baseline: 1.1083x; 1.1083x over previous
//
#include <hip/hip_runtime.h>
#include <stdint.h>

#define BB 64
#define LL 512
#define DD 300
#define CC 128
#define VV 50000

// ws layout (floats):
//   Gpart : [64][32][3][300] = 1,843,200  (non-atomic per-half-block partials)
//   (hole): [64][900]        =    57,600  (legacy Gred slot, unused)
//   W2    : [128][900]       =   115,200  (fused sim.fc weights)
//   bias2 : [128]
#define OFF_GRED  (BB * 32 * 3 * DD)
#define OFF_W2    (OFF_GRED + BB * 3 * DD)
#define OFF_BIAS2 (OFF_W2 + CC * 3 * DD)

// ---------------------------------------------------------------------------
// Kernel 0: embed-table L3 prefetch. The harness's 2x256MiB poison fills
// evict L3 every iteration, so the gather's ~26 MB of unique rows re-fetch
// from HBM in RANDOM order at ~2.2 TB/s effective (round-6 probe: warm
// gather = 16.4 us vs cold ~29 us). Streaming the whole 60 MB table
// linearly costs ~9.5 us at ~6.3 TB/s and converts the gather's misses
// into L3 hits — trading the ~12-14 us random premium for a ~10 us stream.
// acc kept live via asm sink (no DCE), no output writes.
// ---------------------------------------------------------------------------
__global__ __launch_bounds__(256) void k_prefetch(
    const float* __restrict__ embed) {
  const size_t n4 = (size_t)VV * DD / 4;  // 3,750,000 float4
  float4 acc = {0.f, 0.f, 0.f, 0.f};
  for (size_t i = (size_t)blockIdx.x * 256 + threadIdx.x; i < n4;
       i += (size_t)gridDim.x * 256) {
    const float4 v = ((const float4*)embed)[i];
    acc.x += v.x; acc.y += v.y; acc.z += v.z; acc.w += v.w;
  }
  asm volatile("" ::"v"(acc.x), "v"(acc.y), "v"(acc.z), "v"(acc.w));
}

// ---------------------------------------------------------------------------
// Kernel 1: gather + (independent) head-weight precompute, one grid.
// (byte-identical to the verified 128.6 us round-2 version)
// Blocks 0..1023   : gather -> Gpart
// Blocks 1024..1503: W2 precompute
// Blocks 1504..1535: bias2
// ---------------------------------------------------------------------------
__global__ __launch_bounds__(256) void k_gather(
    const int* __restrict__ x, const float* __restrict__ embed,
    const float* __restrict__ conv_w, const float* __restrict__ conv_b,
    const float* __restrict__ w3, const float* __restrict__ b3,
    const float* __restrict__ w4, const float* __restrict__ b4,
    const float* __restrict__ w5, const float* __restrict__ b5,
    const float* __restrict__ fcw, const float* __restrict__ fcb,
    float* __restrict__ Gpart, float* __restrict__ W2,
    float* __restrict__ bias2) {
  const int blk = blockIdx.x;
  const int tid = threadIdx.x;

  if (blk < 1024) {  // ---------------- gather ----------------
    const int b = blk >> 4;
    const int tc = blk & 15;
    const int sub = tid >> 7;    // half-block: 16 tokens each
    const int stid = tid & 127;  // float2 slot

    __shared__ int sx[32];
    __shared__ float su[3][32];

    if (tid < 32) {
      const int t = tc * 32 + tid;
      sx[tid] = x[b * LL + t];
      const float* ws[3] = {w3, w4, w5};
#pragma unroll
      for (int kk = 0; kk < 3; ++kk) {
        const int k = kk + 3;
        int lo = t - k + 1; if (lo < 0) lo = 0;
        int hi = t; const int lim = LL - k - 1; if (hi > lim) hi = lim;
        float s = 0.f;
        for (int l = lo; l <= hi; ++l) s += ws[kk][l];
        su[kk][tid] = s;
      }
    }
    __syncthreads();

    float a0x = 0.f, a0y = 0.f, a1x = 0.f, a1y = 0.f, a2x = 0.f, a2y = 0.f;
    float c0x = 0.f, c0y = 0.f, c1x = 0.f, c1y = 0.f, c2x = 0.f, c2y = 0.f;
    const bool tail = stid < (DD / 2 - 128);  // slots 128..149 -> 22 lanes

#pragma unroll
    for (int half = 0; half < 2; ++half) {
      const int base = sub * 16 + half * 8;
      float2 v[8], u[8];
#pragma unroll
      for (int i = 0; i < 8; ++i) {
        const float2* rp = (const float2*)(embed + (size_t)sx[base + i] * DD);
        v[i] = rp[stid];
      }
      if (tail) {
#pragma unroll
        for (int i = 0; i < 8; ++i) {
          const float2* rp =
              (const float2*)(embed + (size_t)sx[base + i] * DD);
          u[i] = rp[128 + stid];
        }
      }
#pragma unroll
      for (int i = 0; i < 8; ++i) {
        const int j = base + i;
        const float w0 = su[0][j], w1 = su[1][j], w2 = su[2][j];
        a0x += w0 * v[i].x; a0y += w0 * v[i].y;
        a1x += w1 * v[i].x; a1y += w1 * v[i].y;
        a2x += w2 * v[i].x; a2y += w2 * v[i].y;
        if (tail) {
          c0x += w0 * u[i].x; c0y += w0 * u[i].y;
          c1x += w1 * u[i].x; c1y += w1 * u[i].y;
          c2x += w2 * u[i].x; c2y += w2 * u[i].y;
        }
      }
    }

    const int p = tc * 2 + sub;  // 0..31
    float* Gp = Gpart + (size_t)(b * 32 + p) * (3 * DD);
    const int d0 = 2 * stid;
    Gp[0 * DD + d0] = a0x; Gp[0 * DD + d0 + 1] = a0y;
    Gp[1 * DD + d0] = a1x; Gp[1 * DD + d0 + 1] = a1y;
    Gp[2 * DD + d0] = a2x; Gp[2 * DD + d0 + 1] = a2y;
    if (tail) {
      const int d1 = 2 * (128 + stid);
      Gp[0 * DD + d1] = c0x; Gp[0 * DD + d1 + 1] = c0y;
      Gp[1 * DD + d1] = c1x; Gp[1 * DD + d1 + 1] = c1y;
      Gp[2 * DD + d1] = c2x; Gp[2 * DD + d1 + 1] = c2y;
    }
  } else if (blk < 1504) {  // ---------------- W2 precompute ----------------
    const int w = (blk - 1024) * 4 + (tid >> 6);  // 0..1919
    const int lane = tid & 63;
    const int c = w / 15;
    const int rem = w - c * 15;
    const int kk = rem / 5;
    const int chunk = rem - kk * 5;
    const int d = chunk * 64 + lane;
    if (d < DD) {
      const float* fr = fcw + c * (3 * CC) + kk * CC;  // 128 wave-uniform
      float acc0 = 0.f, acc1 = 0.f;
#pragma unroll 4
      for (int cp = 0; cp < CC; cp += 2) {
        acc0 += fr[cp] * conv_w[cp * DD + d];
        acc1 += fr[cp + 1] * conv_w[(cp + 1) * DD + d];
      }
      W2[c * (3 * DD) + kk * DD + d] = acc0 + acc1;
    }
  } else {  // ---------------- bias2 ----------------
    const int wid = tid >> 6;
    const int lane = tid & 63;
    const int c = (blk - 1504) * 4 + wid;  // 0..127
    float sk[3];
    const float* ws[3] = {w3, w4, w5};
#pragma unroll
    for (int kk = 0; kk < 3; ++kk) {
      const int len = LL - (kk + 3);
      float s = 0.f;
      for (int l = lane; l < len; l += 64) s += ws[kk][l];
#pragma unroll
      for (int off = 32; off >= 1; off >>= 1) s += __shfl_down(s, off, 64);
      sk[kk] = __shfl(s, 0, 64);
    }
    const float bkv[3] = {b3[0], b4[0], b5[0]};
    float acc = 0.f;
#pragma unroll
    for (int s6 = 0; s6 < 6; ++s6) {
      const int j = s6 * 64 + lane;
      const int kk = j >> 7;
      const int cp = j & 127;
      acc += fcw[c * (3 * CC) + j] * (conv_b[cp] * sk[kk] + bkv[kk]);
    }
#pragma unroll
    for (int off = 32; off >= 1; off >>= 1) acc += __shfl_down(acc, off, 64);
    if (lane == 0) bias2[c] = acc + fcb[c];
  }
}

// ---------------------------------------------------------------------------
// Kernel 2: fused reduce + head GEMV (verified round-2 version).
// 256 blocks x 256 threads. Block (b, cgrp = blk&3):
//   1) reduce Gpart[b][0..31][900] -> LDS gred[900]
//   2) GEMV 32 channels (cgrp*32..+31), 8 per wave as 4 sequential pairs.
// ---------------------------------------------------------------------------
__global__ __launch_bounds__(256) void k_redout(
    const float* __restrict__ Gpart, const float* __restrict__ W2,
    const float* __restrict__ bias2, float* __restrict__ out) {
  const int b = blockIdx.x >> 2;     // 0..63
  const int cgrp = blockIdx.x & 3;   // channel group of 32
  const int tid = threadIdx.x;
  __shared__ float gred[3 * DD];     // 900 floats = 225 float4

  if (tid < 225) {
    const float4* gp = (const float4*)Gpart + (size_t)b * 32 * 225 + tid;
    float4 s = gp[0];
#pragma unroll
    for (int p = 1; p < 32; ++p) {
      const float4 v = gp[(size_t)p * 225];
      s.x += v.x; s.y += v.y; s.z += v.z; s.w += v.w;
    }
    ((float4*)gred)[tid] = s;
  }
  __syncthreads();

  const int w = tid >> 6;
  const int lane = tid & 63;
  const float2* gr = (const float2*)gred;  // 450 float2
#pragma unroll
  for (int pair = 0; pair < 4; ++pair) {
    const int c0 = cgrp * 32 + w * 8 + pair * 2;
    const float2* wr0 = (const float2*)(W2 + c0 * (3 * DD));
    const float2* wr1 = (const float2*)(W2 + (c0 + 1) * (3 * DD));
    float a0 = 0.f, a1 = 0.f;
#pragma unroll
    for (int s = 0; s < 7; ++s) {
      const float2 g = gr[s * 64 + lane];
      const float2 va = wr0[s * 64 + lane];
      const float2 vb = wr1[s * 64 + lane];
      a0 += va.x * g.x + va.y * g.y;
      a1 += vb.x * g.x + vb.y * g.y;
    }
    if (lane < 2) {
      const float2 g = gr[448 + lane];
      const float2 va = wr0[448 + lane];
      const float2 vb = wr1[448 + lane];
      a0 += va.x * g.x + va.y * g.y;
      a1 += vb.x * g.x + vb.y * g.y;
    }
#pragma unroll
    for (int off = 32; off >= 1; off >>= 1) {
      a0 += __shfl_down(a0, off, 64);
      a1 += __shfl_down(a1, off, 64);
    }
    if (lane == 0) {
      out[b * CC + c0] = a0 + bias2[c0];
      out[b * CC + c0 + 1] = a1 + bias2[c0 + 1];
    }
  }
}

// ---------------------------------------------------------------------------
extern "C" void kernel_launch(void* const* d_in, const int* in_sizes, int n_in,
                              void* d_out, int out_size, void* d_ws,
                              size_t ws_size, hipStream_t stream) {
  const int* x = (const int*)d_in[0];
  const float* embed = (const float*)d_in[1];
  const float* conv_w = (const float*)d_in[2];
  const float* conv_b = (const float*)d_in[3];
  const float* fc3w = (const float*)d_in[4];
  const float* fc3b = (const float*)d_in[5];
  const float* fc4w = (const float*)d_in[6];
  const float* fc4b = (const float*)d_in[7];
  const float* fc5w = (const float*)d_in[8];
  const float* fc5b = (const float*)d_in[9];
  const float* fcw = (const float*)d_in[10];
  const float* fcb = (const float*)d_in[11];

  float* Gpart = (float*)d_ws;
  float* W2 = (float*)d_ws + OFF_W2;
  float* bias2 = (float*)d_ws + OFF_BIAS2;

  k_prefetch<<<dim3(2048), dim3(256), 0, stream>>>(embed);
  k_gather<<<dim3(1536), dim3(256), 0, stream>>>(
      x, embed, conv_w, conv_b, fc3w, fc3b, fc4w, fc4b, fc5w, fc5b, fcw, fcb,
      Gpart, W2, bias2);
  k_redout<<<dim3(256), dim3(256), 0, stream>>>(Gpart, W2, bias2,
                                                (float*)d_out);
}

// Round 8
// 129.334 us; speedup vs baseline: 1.1422x; 1.0306x over previous
//
#include <hip/hip_runtime.h>
#include <stdint.h>

#define BB 64
#define LL 512
#define DD 300
#define CC 128

// ws layout (floats):
//   Gpart : [64][32][3][300] = 1,843,200  (non-atomic per-half-block partials)
//   (hole): [64][900]        =    57,600  (legacy Gred slot, unused)
//   W2    : [128][900]       =   115,200  (fused sim.fc weights)
//   bias2 : [128]
#define OFF_GRED  (BB * 32 * 3 * DD)
#define OFF_W2    (OFF_GRED + BB * 3 * DD)
#define OFF_BIAS2 (OFF_W2 + CC * 3 * DD)

// ---------------------------------------------------------------------------
// Session-final structure (verified 128.6 us, round 2; re-verified here after
// reverting the round-7 prefetch experiment).
//
// Measured budget (rounds 3-7 probes):
//   ~86 us  2x268MB harness poison fills (timed, ~6.3 TB/s, untouchable)
//   ~29 us  gather: 16.4 us L3-warm floor (latency-bound; ILP/occupancy/
//           layout-insensitive — R4/R5) + ~13 us random-row HBM premium
//           (26 MB unique rows; pre-streaming costs more than it saves — R7)
//   ~10 us  epilogue+gaps (三 structural variants all within noise)
// ---------------------------------------------------------------------------
__global__ __launch_bounds__(256) void k_gather(
    const int* __restrict__ x, const float* __restrict__ embed,
    const float* __restrict__ conv_w, const float* __restrict__ conv_b,
    const float* __restrict__ w3, const float* __restrict__ b3,
    const float* __restrict__ w4, const float* __restrict__ b4,
    const float* __restrict__ w5, const float* __restrict__ b5,
    const float* __restrict__ fcw, const float* __restrict__ fcb,
    float* __restrict__ Gpart, float* __restrict__ W2,
    float* __restrict__ bias2) {
  const int blk = blockIdx.x;
  const int tid = threadIdx.x;

  if (blk < 1024) {  // ---------------- gather ----------------
    const int b = blk >> 4;
    const int tc = blk & 15;
    const int sub = tid >> 7;    // half-block: 16 tokens each
    const int stid = tid & 127;  // float2 slot

    __shared__ int sx[32];
    __shared__ float su[3][32];

    if (tid < 32) {
      const int t = tc * 32 + tid;
      sx[tid] = x[b * LL + t];
      const float* ws[3] = {w3, w4, w5};
#pragma unroll
      for (int kk = 0; kk < 3; ++kk) {
        const int k = kk + 3;
        int lo = t - k + 1; if (lo < 0) lo = 0;
        int hi = t; const int lim = LL - k - 1; if (hi > lim) hi = lim;
        float s = 0.f;
        for (int l = lo; l <= hi; ++l) s += ws[kk][l];
        su[kk][tid] = s;
      }
    }
    __syncthreads();

    float a0x = 0.f, a0y = 0.f, a1x = 0.f, a1y = 0.f, a2x = 0.f, a2y = 0.f;
    float c0x = 0.f, c0y = 0.f, c1x = 0.f, c1y = 0.f, c2x = 0.f, c2y = 0.f;
    const bool tail = stid < (DD / 2 - 128);  // slots 128..149 -> 22 lanes

#pragma unroll
    for (int half = 0; half < 2; ++half) {
      const int base = sub * 16 + half * 8;
      float2 v[8], u[8];
#pragma unroll
      for (int i = 0; i < 8; ++i) {
        const float2* rp = (const float2*)(embed + (size_t)sx[base + i] * DD);
        v[i] = rp[stid];
      }
      if (tail) {
#pragma unroll
        for (int i = 0; i < 8; ++i) {
          const float2* rp =
              (const float2*)(embed + (size_t)sx[base + i] * DD);
          u[i] = rp[128 + stid];
        }
      }
#pragma unroll
      for (int i = 0; i < 8; ++i) {
        const int j = base + i;
        const float w0 = su[0][j], w1 = su[1][j], w2 = su[2][j];
        a0x += w0 * v[i].x; a0y += w0 * v[i].y;
        a1x += w1 * v[i].x; a1y += w1 * v[i].y;
        a2x += w2 * v[i].x; a2y += w2 * v[i].y;
        if (tail) {
          c0x += w0 * u[i].x; c0y += w0 * u[i].y;
          c1x += w1 * u[i].x; c1y += w1 * u[i].y;
          c2x += w2 * u[i].x; c2y += w2 * u[i].y;
        }
      }
    }

    const int p = tc * 2 + sub;  // 0..31
    float* Gp = Gpart + (size_t)(b * 32 + p) * (3 * DD);
    const int d0 = 2 * stid;
    Gp[0 * DD + d0] = a0x; Gp[0 * DD + d0 + 1] = a0y;
    Gp[1 * DD + d0] = a1x; Gp[1 * DD + d0 + 1] = a1y;
    Gp[2 * DD + d0] = a2x; Gp[2 * DD + d0 + 1] = a2y;
    if (tail) {
      const int d1 = 2 * (128 + stid);
      Gp[0 * DD + d1] = c0x; Gp[0 * DD + d1 + 1] = c0y;
      Gp[1 * DD + d1] = c1x; Gp[1 * DD + d1 + 1] = c1y;
      Gp[2 * DD + d1] = c2x; Gp[2 * DD + d1 + 1] = c2y;
    }
  } else if (blk < 1504) {  // ---------------- W2 precompute ----------------
    const int w = (blk - 1024) * 4 + (tid >> 6);  // 0..1919
    const int lane = tid & 63;
    const int c = w / 15;
    const int rem = w - c * 15;
    const int kk = rem / 5;
    const int chunk = rem - kk * 5;
    const int d = chunk * 64 + lane;
    if (d < DD) {
      const float* fr = fcw + c * (3 * CC) + kk * CC;  // 128 wave-uniform
      float acc0 = 0.f, acc1 = 0.f;
#pragma unroll 4
      for (int cp = 0; cp < CC; cp += 2) {
        acc0 += fr[cp] * conv_w[cp * DD + d];
        acc1 += fr[cp + 1] * conv_w[(cp + 1) * DD + d];
      }
      W2[c * (3 * DD) + kk * DD + d] = acc0 + acc1;
    }
  } else {  // ---------------- bias2 ----------------
    const int wid = tid >> 6;
    const int lane = tid & 63;
    const int c = (blk - 1504) * 4 + wid;  // 0..127
    float sk[3];
    const float* ws[3] = {w3, w4, w5};
#pragma unroll
    for (int kk = 0; kk < 3; ++kk) {
      const int len = LL - (kk + 3);
      float s = 0.f;
      for (int l = lane; l < len; l += 64) s += ws[kk][l];
#pragma unroll
      for (int off = 32; off >= 1; off >>= 1) s += __shfl_down(s, off, 64);
      sk[kk] = __shfl(s, 0, 64);
    }
    const float bkv[3] = {b3[0], b4[0], b5[0]};
    float acc = 0.f;
#pragma unroll
    for (int s6 = 0; s6 < 6; ++s6) {
      const int j = s6 * 64 + lane;
      const int kk = j >> 7;
      const int cp = j & 127;
      acc += fcw[c * (3 * CC) + j] * (conv_b[cp] * sk[kk] + bkv[kk]);
    }
#pragma unroll
    for (int off = 32; off >= 1; off >>= 1) acc += __shfl_down(acc, off, 64);
    if (lane == 0) bias2[c] = acc + fcb[c];
  }
}

// ---------------------------------------------------------------------------
// Kernel 2: fused reduce + head GEMV (verified round-2 version).
// 256 blocks x 256 threads. Block (b, cgrp = blk&3):
//   1) reduce Gpart[b][0..31][900] -> LDS gred[900]
//   2) GEMV 32 channels (cgrp*32..+31), 8 per wave as 4 sequential pairs.
// ---------------------------------------------------------------------------
__global__ __launch_bounds__(256) void k_redout(
    const float* __restrict__ Gpart, const float* __restrict__ W2,
    const float* __restrict__ bias2, float* __restrict__ out) {
  const int b = blockIdx.x >> 2;     // 0..63
  const int cgrp = blockIdx.x & 3;   // channel group of 32
  const int tid = threadIdx.x;
  __shared__ float gred[3 * DD];     // 900 floats = 225 float4

  if (tid < 225) {
    const float4* gp = (const float4*)Gpart + (size_t)b * 32 * 225 + tid;
    float4 s = gp[0];
#pragma unroll
    for (int p = 1; p < 32; ++p) {
      const float4 v = gp[(size_t)p * 225];
      s.x += v.x; s.y += v.y; s.z += v.z; s.w += v.w;
    }
    ((float4*)gred)[tid] = s;
  }
  __syncthreads();

  const int w = tid >> 6;
  const int lane = tid & 63;
  const float2* gr = (const float2*)gred;  // 450 float2
#pragma unroll
  for (int pair = 0; pair < 4; ++pair) {
    const int c0 = cgrp * 32 + w * 8 + pair * 2;
    const float2* wr0 = (const float2*)(W2 + c0 * (3 * DD));
    const float2* wr1 = (const float2*)(W2 + (c0 + 1) * (3 * DD));
    float a0 = 0.f, a1 = 0.f;
#pragma unroll
    for (int s = 0; s < 7; ++s) {
      const float2 g = gr[s * 64 + lane];
      const float2 va = wr0[s * 64 + lane];
      const float2 vb = wr1[s * 64 + lane];
      a0 += va.x * g.x + va.y * g.y;
      a1 += vb.x * g.x + vb.y * g.y;
    }
    if (lane < 2) {
      const float2 g = gr[448 + lane];
      const float2 va = wr0[448 + lane];
      const float2 vb = wr1[448 + lane];
      a0 += va.x * g.x + va.y * g.y;
      a1 += vb.x * g.x + vb.y * g.y;
    }
#pragma unroll
    for (int off = 32; off >= 1; off >>= 1) {
      a0 += __shfl_down(a0, off, 64);
      a1 += __shfl_down(a1, off, 64);
    }
    if (lane == 0) {
      out[b * CC + c0] = a0 + bias2[c0];
      out[b * CC + c0 + 1] = a1 + bias2[c0 + 1];
    }
  }
}

// ---------------------------------------------------------------------------
extern "C" void kernel_launch(void* const* d_in, const int* in_sizes, int n_in,
                              void* d_out, int out_size, void* d_ws,
                              size_t ws_size, hipStream_t stream) {
  const int* x = (const int*)d_in[0];
  const float* embed = (const float*)d_in[1];
  const float* conv_w = (const float*)d_in[2];
  const float* conv_b = (const float*)d_in[3];
  const float* fc3w = (const float*)d_in[4];
  const float* fc3b = (const float*)d_in[5];
  const float* fc4w = (const float*)d_in[6];
  const float* fc4b = (const float*)d_in[7];
  const float* fc5w = (const float*)d_in[8];
  const float* fc5b = (const float*)d_in[9];
  const float* fcw = (const float*)d_in[10];
  const float* fcb = (const float*)d_in[11];

  float* Gpart = (float*)d_ws;
  float* W2 = (float*)d_ws + OFF_W2;
  float* bias2 = (float*)d_ws + OFF_BIAS2;

  k_gather<<<dim3(1536), dim3(256), 0, stream>>>(
      x, embed, conv_w, conv_b, fc3w, fc3b, fc4w, fc4b, fc5w, fc5b, fcw, fcb,
      Gpart, W2, bias2);
  k_redout<<<dim3(256), dim3(256), 0, stream>>>(Gpart, W2, bias2,
                                                (float*)d_out);
}